// Round 1
// 1724.456 us; speedup vs baseline: 1.0942x; 1.0942x over previous
//
#include <hip/hip_runtime.h>
#include <hip/hip_bf16.h>

#define B_N   64
#define Q_N   2048
#define K_N   2048
#define D_N   128
#define NEGV  (-1e9f)
#define SCALE 0.08838834764831845f   // 1/sqrt(128)

using f32x4  = __attribute__((ext_vector_type(4))) float;
using bf16x8 = __attribute__((ext_vector_type(8))) short;

static __device__ __forceinline__ short tobf(float f) {
  __hip_bfloat16 h = __float2bfloat16(f);   // RNE
  return __builtin_bit_cast(short, h);
}

// Per-workgroup: one batch b, 64 q-rows (q0..q0+63). 4 waves, wave w owns rows
// q0+w*16..+15 for QK^T/softmax. Two passes over K, but ONLY over the live
// region [0, round_up64(vlen)); the masked tail of attn is exactly 0.0f in the
// fp32 reference (exp(-1e9 - m) underflows), so it is vector-zero-filled.
// vlen==0 (uniform softmax = 1/2048) falls back to the full masked loop.
__global__ __launch_bounds__(256, 2)
void attn_fused(const float* __restrict__ Qg, const float* __restrict__ Kg,
                const float* __restrict__ Vg, const int* __restrict__ vlg,
                float* __restrict__ outp, float* __restrict__ attnp)
{
  __shared__ __align__(16) short Kst[64 * 136];  // K-tile bf16, row stride 136 (pad 8)
  __shared__ __align__(16) short Vst[64 * 136];  // V-tile bf16 (pass B only)
  __shared__ __align__(16) short Pt [64 * 68];   // P^T bf16: [key 0..63][row 0..63], stride 68

  // XCD swizzle: all 32 tiles of batch b land on XCD b%8 (blockIdx%8 heuristic)
  const int id   = blockIdx.x;
  const int xcd  = id & 7;
  const int rest = id >> 3;
  const int b    = (rest >> 5) * 8 + xcd;
  const int q0   = (rest & 31) * 64;

  const int tid  = threadIdx.x;
  const int w    = tid >> 6;
  const int lane = tid & 63;
  const int m16  = lane & 15;
  const int quad = lane >> 4;

  const int vlen = vlg[b];
  // live-compute region end (multiple of 64). vlen==0 -> full loop (uniform row).
  const int kT   = (vlen == 0) ? K_N : ((vlen + 63) & ~63);

  const float* Qb = Qg + (size_t)b * Q_N * D_N;
  const float* Kb = Kg + (size_t)b * K_N * D_N;
  const float* Vb = Vg + (size_t)b * K_N * D_N;

  // ---- zero-fill masked attn tail: rows q0..q0+63, cols [kT, K_N) ----
  {
    float* arow = attnp + ((size_t)b * Q_N + q0 + (tid >> 2)) * K_N;
    const f32x4 z = {0.f, 0.f, 0.f, 0.f};
    for (int col = kT + (tid & 3) * 4; col < K_N; col += 16)
      __builtin_nontemporal_store(z, (f32x4*)(arow + col));
  }

  // ---- Q fragments (A-layout: A[m=lane&15][k=quad*8+j]), rows q0+w*16+m16 ----
  bf16x8 aQ[4];
  {
    const float* qr = Qb + (size_t)(q0 + w*16 + m16) * D_N + quad*8;
    #pragma unroll
    for (int d0 = 0; d0 < 4; ++d0) {
      float4 f0 = *(const float4*)(qr + d0*32);
      float4 f1 = *(const float4*)(qr + d0*32 + 4);
      bf16x8 a;
      a[0]=tobf(f0.x); a[1]=tobf(f0.y); a[2]=tobf(f0.z); a[3]=tobf(f0.w);
      a[4]=tobf(f1.x); a[5]=tobf(f1.y); a[6]=tobf(f1.z); a[7]=tobf(f1.w);
      aQ[d0] = a;
    }
  }

  // cooperative stage of a 64x128 tile (fp32 global -> bf16 LDS, stride 136)
  auto stage64x128 = [&](const float* __restrict__ srcB, int k0, short* dst) {
    #pragma unroll
    for (int i = 0; i < 4; ++i) {
      int c   = i*256 + tid;
      int row = c >> 4;
      int col = (c & 15) << 3;
      const float* src = srcB + (size_t)(k0 + row) * D_N + col;
      float4 f0 = *(const float4*)(src);
      float4 f1 = *(const float4*)(src + 4);
      bf16x8 v;
      v[0]=tobf(f0.x); v[1]=tobf(f0.y); v[2]=tobf(f0.z); v[3]=tobf(f0.w);
      v[4]=tobf(f1.x); v[5]=tobf(f1.y); v[6]=tobf(f1.z); v[7]=tobf(f1.w);
      *(bf16x8*)&dst[row*136 + col] = v;
    }
  };

  #define QMAX(v) { v = fmaxf(v, __shfl_xor(v, 1)); v = fmaxf(v, __shfl_xor(v, 2)); \
                    v = fmaxf(v, __shfl_xor(v, 4)); v = fmaxf(v, __shfl_xor(v, 8)); }
  #define QSUM(v) { v += __shfl_xor(v, 1); v += __shfl_xor(v, 2); \
                    v += __shfl_xor(v, 4); v += __shfl_xor(v, 8); }

  // ================= pass A: online (m, l) per row, 64-key tile granularity ===
  float m_r[4], l_r[4];
  #pragma unroll
  for (int r = 0; r < 4; ++r) { m_r[r] = -INFINITY; l_r[r] = 0.0f; }

  for (int k0 = 0; k0 < kT; k0 += 64) {
    __syncthreads();          // protect Kst vs previous iter's reads
    stage64x128(Kb, k0, Kst);
    __syncthreads();

    f32x4 acc[4];
    #pragma unroll
    for (int kt = 0; kt < 4; ++kt) acc[kt] = (f32x4){0.f,0.f,0.f,0.f};
    #pragma unroll
    for (int kt = 0; kt < 4; ++kt)
      #pragma unroll
      for (int d0 = 0; d0 < 4; ++d0) {
        bf16x8 bk = *(const bf16x8*)&Kst[(kt*16 + m16)*136 + d0*32 + quad*8];
        acc[kt] = __builtin_amdgcn_mfma_f32_16x16x32_bf16(aQ[d0], bk, acc[kt], 0, 0, 0);
      }

    const int key0 = k0 + m16;
    const bool mk0 = (key0     ) >= vlen;
    const bool mk1 = (key0 + 16) >= vlen;
    const bool mk2 = (key0 + 32) >= vlen;
    const bool mk3 = (key0 + 48) >= vlen;
    #pragma unroll
    for (int r = 0; r < 4; ++r) {          // D-layout: row=quad*4+r, col=m16
      float s0 = mk0 ? NEGV : acc[0][r] * SCALE;
      float s1 = mk1 ? NEGV : acc[1][r] * SCALE;
      float s2 = mk2 ? NEGV : acc[2][r] * SCALE;
      float s3 = mk3 ? NEGV : acc[3][r] * SCALE;
      float tm = fmaxf(fmaxf(s0, s1), fmaxf(s2, s3));
      QMAX(tm);
      float mn = fmaxf(m_r[r], tm);
      float p  = __expf(s0 - mn) + __expf(s1 - mn) + __expf(s2 - mn) + __expf(s3 - mn);
      QSUM(p);
      l_r[r] = l_r[r] * __expf(m_r[r] - mn) + p;
      m_r[r] = mn;
    }
  }
  float inv_l[4];
  #pragma unroll
  for (int r = 0; r < 4; ++r) inv_l[r] = 1.0f / l_r[r];

  // ================= pass B: recompute S, write attn, PV =================
  f32x4 accO[4][2];   // out tile: rows mt*16+(quad*4+r), cols w*32 + nt*16 + m16
  #pragma unroll
  for (int mt = 0; mt < 4; ++mt)
    #pragma unroll
    for (int nt = 0; nt < 2; ++nt)
      accO[mt][nt] = (f32x4){0.f, 0.f, 0.f, 0.f};

  for (int k0 = 0; k0 < kT; k0 += 64) {
    __syncthreads();          // protect Kst/Vst/Pt vs previous iter's reads
    stage64x128(Kb, k0, Kst);
    stage64x128(Vb, k0, Vst);
    __syncthreads();

    // S for own 16 rows; normalized P -> global attn (nontemporal) + LDS P^T
    f32x4 acc[4];
    #pragma unroll
    for (int kt = 0; kt < 4; ++kt) acc[kt] = (f32x4){0.f,0.f,0.f,0.f};
    #pragma unroll
    for (int kt = 0; kt < 4; ++kt)
      #pragma unroll
      for (int d0 = 0; d0 < 4; ++d0) {
        bf16x8 bk = *(const bf16x8*)&Kst[(kt*16 + m16)*136 + d0*32 + quad*8];
        acc[kt] = __builtin_amdgcn_mfma_f32_16x16x32_bf16(aQ[d0], bk, acc[kt], 0, 0, 0);
      }

    #pragma unroll
    for (int kt = 0; kt < 4; ++kt) {
      const int key = k0 + kt*16 + m16;
      const bool msk = key >= vlen;
      float pv[4];
      #pragma unroll
      for (int r = 0; r < 4; ++r) {
        float s = msk ? NEGV : acc[kt][r] * SCALE;
        pv[r] = __expf(s - m_r[r]) * inv_l[r];   // masked -> underflow to 0 (vlen>0)
      }
      float* ap = attnp + ((size_t)b * Q_N + q0 + w*16 + quad*4) * K_N + key;
      #pragma unroll
      for (int r = 0; r < 4; ++r)
        __builtin_nontemporal_store(pv[r], ap + (size_t)r * K_N);
      // P^T: Pt[key_local][row_local]; lane holds 4 consecutive rows -> one b64
      short4 pk = make_short4(tobf(pv[0]), tobf(pv[1]), tobf(pv[2]), tobf(pv[3]));
      *(short4*)&Pt[(kt*16 + m16)*68 + w*16 + quad*4] = pk;
    }
    __syncthreads();          // Pt complete

    // PV: out[64 x 128] += P[64 x 64-tile] * V[64-tile x 128]; wave w owns d-cols [w*32, w*32+32)
    #pragma unroll
    for (int c = 0; c < 2; ++c) {          // 32-wide k-chunks
      bf16x8 aP[4];
      #pragma unroll
      for (int mt = 0; mt < 4; ++mt) {     // A[m=mt*16+m16][k=c*32+quad*8+j] = Pt[k][row]
        bf16x8 a;
        #pragma unroll
        for (int j = 0; j < 8; ++j)
          a[j] = Pt[(c*32 + quad*8 + j)*68 + mt*16 + m16];
        aP[mt] = a;
      }
      #pragma unroll
      for (int nt = 0; nt < 2; ++nt) {
        const int vcol = w*32 + nt*16 + m16;
        bf16x8 bv;                          // B[k=quad*8+j][n=m16] = Vst[c*32+k][d]
        #pragma unroll
        for (int j = 0; j < 8; ++j) bv[j] = Vst[(c*32 + quad*8 + j)*136 + vcol];
        #pragma unroll
        for (int mt = 0; mt < 4; ++mt)
          accO[mt][nt] = __builtin_amdgcn_mfma_f32_16x16x32_bf16(aP[mt], bv, accO[mt][nt], 0, 0, 0);
      }
    }
  }

  // ================= epilogue: out store =================
  #pragma unroll
  for (int mt = 0; mt < 4; ++mt)
    #pragma unroll
    for (int nt = 0; nt < 2; ++nt)
      #pragma unroll
      for (int r = 0; r < 4; ++r) {
        int row = q0 + mt*16 + quad*4 + r;
        int col = w*32 + nt*16 + m16;
        __builtin_nontemporal_store(accO[mt][nt][r],
                                    outp + ((size_t)b * Q_N + row) * D_N + col);
      }
}

extern "C" void kernel_launch(void* const* d_in, const int* in_sizes, int n_in,
                              void* d_out, int out_size, void* d_ws, size_t ws_size,
                              hipStream_t stream) {
  const float* Q  = (const float*)d_in[0];
  const float* K  = (const float*)d_in[1];
  const float* V  = (const float*)d_in[2];
  const int*   vl = (const int*)d_in[3];
  float* outp  = (float*)d_out;
  float* attnp = outp + (size_t)B_N * Q_N * D_N;   // tuple: (out, attn) concatenated

  dim3 grid(B_N * (Q_N / 64));   // 2048 WGs
  dim3 block(256);
  hipLaunchKernelGGL(attn_fused, grid, block, 0, stream, Q, K, V, vl, outp, attnp);
}

// Round 2
// 1678.714 us; speedup vs baseline: 1.1240x; 1.0272x over previous
//
#include <hip/hip_runtime.h>
#include <hip/hip_bf16.h>

#define B_N   64
#define Q_N   2048
#define K_N   2048
#define D_N   128
#define NEGV  (-1e9f)
#define SCALE 0.08838834764831845f   // 1/sqrt(128)

using f32x4  = __attribute__((ext_vector_type(4))) float;
using bf16x8 = __attribute__((ext_vector_type(8))) short;

static __device__ __forceinline__ short tobf(float f) {
  __hip_bfloat16 h = __float2bfloat16(f);   // RNE
  return __builtin_bit_cast(short, h);
}

// Per-workgroup: one batch b, 64 q-rows. 4 waves; wave w owns rows q0+w*16..+15
// for QK^T/softmax. Two passes over the live region [0, round_up64(vlen)); the
// masked attn tail is exactly 0.0f in the fp32 reference (exp underflow) and is
// vector-zero-filled. vlen==0 falls back to the full masked loop (uniform row).
// K tiles are double-staged: global->regs issued one tile ahead (T14), regs->LDS
// written just-in-time. V is read directly from global (L2-resident: 32 WGs of a
// batch share the panel on one XCD). P is stored ROW-major in LDS (b128 reads
// for the PV A-fragment) with a bit-3 XOR swizzle to break quad write conflicts.
__global__ __launch_bounds__(256, 4)
void attn_fused(const float* __restrict__ Qg, const float* __restrict__ Kg,
                const float* __restrict__ Vg, const int* __restrict__ vlg,
                float* __restrict__ outp, float* __restrict__ attnp)
{
  __shared__ __align__(16) short Kst[64 * 136];  // K-tile bf16, row stride 136 (pad 8)
  __shared__ __align__(16) short Pst[64 * 72];   // P bf16 row-major [row][key], stride 72, XOR-swz

  // XCD swizzle: all 32 tiles of batch b land on XCD b%8
  const int id   = blockIdx.x;
  const int xcd  = id & 7;
  const int rest = id >> 3;
  const int b    = (rest >> 5) * 8 + xcd;
  const int q0   = (rest & 31) * 64;

  const int tid  = threadIdx.x;
  const int w    = tid >> 6;
  const int lane = tid & 63;
  const int m16  = lane & 15;
  const int quad = lane >> 4;

  const int vlen = vlg[b];
  const int kT   = (vlen == 0) ? K_N : ((vlen + 63) & ~63);

  const float* Qb = Qg + (size_t)b * Q_N * D_N;
  const float* Kb = Kg + (size_t)b * K_N * D_N;
  const float* Vb = Vg + (size_t)b * K_N * D_N;

  // ---- zero-fill masked attn tail: rows q0..q0+63, cols [kT, K_N) ----
  {
    float* arow = attnp + ((size_t)b * Q_N + q0 + (tid >> 2)) * K_N;
    const f32x4 z = {0.f, 0.f, 0.f, 0.f};
    for (int col = kT + (tid & 3) * 4; col < K_N; col += 16)
      __builtin_nontemporal_store(z, (f32x4*)(arow + col));
  }

  // ---- Q fragments (A-layout: A[m=lane&15][k=quad*8+j]), rows q0+w*16+m16 ----
  bf16x8 aQ[4];
  {
    const float* qr = Qb + (size_t)(q0 + w*16 + m16) * D_N + quad*8;
    #pragma unroll
    for (int d0 = 0; d0 < 4; ++d0) {
      float4 f0 = *(const float4*)(qr + d0*32);
      float4 f1 = *(const float4*)(qr + d0*32 + 4);
      bf16x8 a;
      a[0]=tobf(f0.x); a[1]=tobf(f0.y); a[2]=tobf(f0.z); a[3]=tobf(f0.w);
      a[4]=tobf(f1.x); a[5]=tobf(f1.y); a[6]=tobf(f1.z); a[7]=tobf(f1.w);
      aQ[d0] = a;
    }
  }

  // ---- K staging: global -> regs (issued a tile early) -> bf16 LDS ----
  const int srow = tid >> 4;          // 0..15, +i*16
  const int scol = (tid & 15) << 3;   // 0..120 step 8
  float4 kf[4][2];
  auto load_K = [&](int k0) {
    #pragma unroll
    for (int i = 0; i < 4; ++i) {
      const float* src = Kb + (size_t)(k0 + i*16 + srow) * D_N + scol;
      kf[i][0] = *(const float4*)(src);
      kf[i][1] = *(const float4*)(src + 4);
    }
  };
  auto write_K = [&]() {
    #pragma unroll
    for (int i = 0; i < 4; ++i) {
      bf16x8 v;
      v[0]=tobf(kf[i][0].x); v[1]=tobf(kf[i][0].y); v[2]=tobf(kf[i][0].z); v[3]=tobf(kf[i][0].w);
      v[4]=tobf(kf[i][1].x); v[5]=tobf(kf[i][1].y); v[6]=tobf(kf[i][1].z); v[7]=tobf(kf[i][1].w);
      *(bf16x8*)&Kst[(i*16 + srow)*136 + scol] = v;
    }
  };

  #define QMAX(v) { v = fmaxf(v, __shfl_xor(v, 1)); v = fmaxf(v, __shfl_xor(v, 2)); \
                    v = fmaxf(v, __shfl_xor(v, 4)); v = fmaxf(v, __shfl_xor(v, 8)); }
  #define QSUM(v) { v += __shfl_xor(v, 1); v += __shfl_xor(v, 2); \
                    v += __shfl_xor(v, 4); v += __shfl_xor(v, 8); }

  // ================= pass A: online (m, l) per row, 64-key tile granularity ===
  float m_r[4], l_r[4];
  #pragma unroll
  for (int r = 0; r < 4; ++r) { m_r[r] = -INFINITY; l_r[r] = 0.0f; }

  load_K(0);
  for (int k0 = 0; k0 < kT; k0 += 64) {
    __syncthreads();          // previous iter's Kst reads done
    write_K();
    if (k0 + 64 < kT) load_K(k0 + 64);   // prefetch next tile (latency hidden)
    __syncthreads();

    f32x4 acc[4];
    #pragma unroll
    for (int kt = 0; kt < 4; ++kt) acc[kt] = (f32x4){0.f,0.f,0.f,0.f};
    #pragma unroll
    for (int kt = 0; kt < 4; ++kt)
      #pragma unroll
      for (int d0 = 0; d0 < 4; ++d0) {
        bf16x8 bk = *(const bf16x8*)&Kst[(kt*16 + m16)*136 + d0*32 + quad*8];
        acc[kt] = __builtin_amdgcn_mfma_f32_16x16x32_bf16(aQ[d0], bk, acc[kt], 0, 0, 0);
      }

    const int key0 = k0 + m16;
    const bool mk0 = (key0     ) >= vlen;
    const bool mk1 = (key0 + 16) >= vlen;
    const bool mk2 = (key0 + 32) >= vlen;
    const bool mk3 = (key0 + 48) >= vlen;
    #pragma unroll
    for (int r = 0; r < 4; ++r) {          // D-layout: row=quad*4+r, col=m16
      float s0 = mk0 ? NEGV : acc[0][r] * SCALE;
      float s1 = mk1 ? NEGV : acc[1][r] * SCALE;
      float s2 = mk2 ? NEGV : acc[2][r] * SCALE;
      float s3 = mk3 ? NEGV : acc[3][r] * SCALE;
      float tm = fmaxf(fmaxf(s0, s1), fmaxf(s2, s3));
      QMAX(tm);
      float mn = fmaxf(m_r[r], tm);
      float p  = __expf(s0 - mn) + __expf(s1 - mn) + __expf(s2 - mn) + __expf(s3 - mn);
      QSUM(p);
      l_r[r] = l_r[r] * __expf(m_r[r] - mn) + p;
      m_r[r] = mn;
    }
  }
  float inv_l[4];
  #pragma unroll
  for (int r = 0; r < 4; ++r) inv_l[r] = 1.0f / l_r[r];

  // ================= pass B: recompute S, write attn, PV =================
  f32x4 accO[4][2];   // out tile: rows mt*16+(quad*4+r), cols w*32 + nt*16 + m16
  #pragma unroll
  for (int mt = 0; mt < 4; ++mt)
    #pragma unroll
    for (int nt = 0; nt < 2; ++nt)
      accO[mt][nt] = (f32x4){0.f, 0.f, 0.f, 0.f};

  // P write-swizzle: row = w*16+quad*4+r -> bit3 of row is (quad>>1); flip 8-short bit
  const int pwxor = ((quad >> 1) & 1) << 3;
  const int prxor = ((m16 >> 3) & 1) << 3;   // read side: row = mt*16+m16

  load_K(0);
  for (int k0 = 0; k0 < kT; k0 += 64) {
    __syncthreads();          // previous iter's Kst/Pst reads done
    write_K();
    if (k0 + 64 < kT) load_K(k0 + 64);
    __syncthreads();

    // S for own 16 rows; normalized P -> global attn (nontemporal) + LDS P (row-major)
    f32x4 acc[4];
    #pragma unroll
    for (int kt = 0; kt < 4; ++kt) acc[kt] = (f32x4){0.f,0.f,0.f,0.f};
    #pragma unroll
    for (int kt = 0; kt < 4; ++kt)
      #pragma unroll
      for (int d0 = 0; d0 < 4; ++d0) {
        bf16x8 bk = *(const bf16x8*)&Kst[(kt*16 + m16)*136 + d0*32 + quad*8];
        acc[kt] = __builtin_amdgcn_mfma_f32_16x16x32_bf16(aQ[d0], bk, acc[kt], 0, 0, 0);
      }

    #pragma unroll
    for (int kt = 0; kt < 4; ++kt) {
      const int key = k0 + kt*16 + m16;
      const bool msk = key >= vlen;
      float pv[4];
      #pragma unroll
      for (int r = 0; r < 4; ++r) {
        float s = msk ? NEGV : acc[kt][r] * SCALE;
        pv[r] = __expf(s - m_r[r]) * inv_l[r];   // masked -> underflows to 0 (vlen>0)
      }
      float* ap = attnp + ((size_t)b * Q_N + q0 + w*16 + quad*4) * K_N + key;
      #pragma unroll
      for (int r = 0; r < 4; ++r)
        __builtin_nontemporal_store(pv[r], ap + (size_t)r * K_N);
      // P row-major: Pst[row][key], row = w*16+quad*4+r, key = kt*16+m16
      #pragma unroll
      for (int r = 0; r < 4; ++r)
        Pst[(((w*16 + quad*4 + r) * 72) + kt*16 + m16) ^ pwxor] = tobf(pv[r]);
    }
    __syncthreads();          // Pst complete

    // PV: out[64 x 128] += P[64 x 64] * V[64 x 128]; wave w owns d-cols [w*32, w*32+32)
    #pragma unroll
    for (int c = 0; c < 2; ++c) {          // 32-wide k-chunks
      bf16x8 aP[4];
      #pragma unroll
      for (int mt = 0; mt < 4; ++mt)       // A[m=mt*16+m16][k=c*32+quad*8+j] -> b128
        aP[mt] = *(const bf16x8*)&Pst[(((mt*16 + m16) * 72) + c*32 + quad*8) ^ prxor];
      #pragma unroll
      for (int nt = 0; nt < 2; ++nt) {
        const float* vp = Vb + (size_t)(k0 + c*32 + quad*8) * D_N + w*32 + nt*16 + m16;
        bf16x8 bv;                          // B[k=quad*8+j][n=m16] = V[k][d], L2-resident
        #pragma unroll
        for (int j = 0; j < 8; ++j) bv[j] = tobf(vp[(size_t)j * D_N]);
        #pragma unroll
        for (int mt = 0; mt < 4; ++mt)
          accO[mt][nt] = __builtin_amdgcn_mfma_f32_16x16x32_bf16(aP[mt], bv, accO[mt][nt], 0, 0, 0);
      }
    }
  }

  // ================= epilogue: out store =================
  #pragma unroll
  for (int mt = 0; mt < 4; ++mt)
    #pragma unroll
    for (int nt = 0; nt < 2; ++nt)
      #pragma unroll
      for (int r = 0; r < 4; ++r) {
        int row = q0 + mt*16 + quad*4 + r;
        int col = w*32 + nt*16 + m16;
        __builtin_nontemporal_store(accO[mt][nt][r],
                                    outp + ((size_t)b * Q_N + row) * D_N + col);
      }
}

extern "C" void kernel_launch(void* const* d_in, const int* in_sizes, int n_in,
                              void* d_out, int out_size, void* d_ws, size_t ws_size,
                              hipStream_t stream) {
  const float* Q  = (const float*)d_in[0];
  const float* K  = (const float*)d_in[1];
  const float* V  = (const float*)d_in[2];
  const int*   vl = (const int*)d_in[3];
  float* outp  = (float*)d_out;
  float* attnp = outp + (size_t)B_N * Q_N * D_N;   // tuple: (out, attn) concatenated

  dim3 grid(B_N * (Q_N / 64));   // 2048 WGs
  dim3 block(256);
  hipLaunchKernelGGL(attn_fused, grid, block, 0, stream, Q, K, V, vl, outp, attnp);
}